// Round 1
// baseline (315.114 us; speedup 1.0000x reference)
//
#include <hip/hip_runtime.h>

// deltaE (CIEDE2000) color loss: mean over 32x512x512 pixels.
// Memory layout note: reference reshapes (B,3,H,W)->(B,H,W,3) WITHOUT
// transpose, so each pixel's RGB is 3 consecutive floats in the flat array.

__device__ __forceinline__ float pow7f(float x) {
    float x2 = x * x;
    float x3 = x2 * x;
    return x3 * x3 * x;   // x^7
}

__device__ __forceinline__ void rgb2lab(float r, float g, float b,
                                        float& L, float& A, float& B) {
    // sRGB -> linear
    auto lin = [](float v) {
        return (v <= 0.04045f) ? v * (1.0f / 12.92f)
                               : powf((v + 0.055f) * (1.0f / 1.055f), 2.4f);
    };
    float rl = lin(r), gl = lin(g), bl = lin(b);
    // linear RGB -> XYZ (skimage matrix), then / white point
    float x = (0.412453f * rl + 0.357580f * gl + 0.180423f * bl) * (1.0f / 0.95047f);
    float y = (0.212671f * rl + 0.715160f * gl + 0.072169f * bl);
    float z = (0.019334f * rl + 0.119193f * gl + 0.950227f * bl) * (1.0f / 1.08883f);
    auto fxyz = [](float t) {
        return (t > 0.008856f) ? cbrtf(t) : 7.787f * t + (16.0f / 116.0f);
    };
    float fx = fxyz(x), fy = fxyz(y), fz = fxyz(z);
    L = 116.0f * fy - 16.0f;
    A = 500.0f * (fx - fy);
    B = 200.0f * (fy - fz);
}

__device__ __forceinline__ float ciede2000(float L1, float a1, float b1,
                                           float L2, float a2, float b2) {
    const float P25_7   = 6103515625.0f;             // 25^7
    const float RAD2DEG = 57.29577951308232f;
    const float DEG2RAD = 0.017453292519943295f;

    float C1 = sqrtf(fmaf(a1, a1, b1 * b1));
    float C2 = sqrtf(fmaf(a2, a2, b2 * b2));
    float Cbar = 0.5f * (C1 + C2);
    float c7 = pow7f(Cbar);
    float G = 0.5f * (1.0f - sqrtf(c7 / (c7 + P25_7)));
    float a1p = a1 * (1.0f + G);
    float a2p = a2 * (1.0f + G);
    float C1p = sqrtf(fmaf(a1p, a1p, b1 * b1));
    float C2p = sqrtf(fmaf(a2p, a2p, b2 * b2));

    float h1 = atan2f(b1, a1p) * RAD2DEG;
    h1 = fmodf(h1, 360.0f); if (h1 < 0.0f) h1 += 360.0f;
    float h2 = atan2f(b2, a2p) * RAD2DEG;
    h2 = fmodf(h2, 360.0f); if (h2 < 0.0f) h2 += 360.0f;

    float dLp = L2 - L1;
    float dCp = C2p - C1p;
    float CC = C1p * C2p;
    float hdiff = h2 - h1;
    float dh = (hdiff > 180.0f) ? hdiff - 360.0f
             : ((hdiff < -180.0f) ? hdiff + 360.0f : hdiff);
    if (CC == 0.0f) dh = 0.0f;
    float dHp = 2.0f * sqrtf(CC) * sinf(0.5f * dh * DEG2RAD);

    float Lbar = 0.5f * (L1 + L2);
    float Cbarp = 0.5f * (C1p + C2p);
    float hsum = h1 + h2;
    float hbar = (fabsf(h1 - h2) <= 180.0f) ? 0.5f * hsum
               : ((hsum < 360.0f) ? 0.5f * (hsum + 360.0f)
                                  : 0.5f * (hsum - 360.0f));
    if (CC == 0.0f) hbar = hsum;
    float hr = hbar * DEG2RAD;
    float T = 1.0f
            - 0.17f * cosf(hr - 30.0f * DEG2RAD)
            + 0.24f * cosf(2.0f * hr)
            + 0.32f * cosf(3.0f * hr + 6.0f * DEG2RAD)
            - 0.20f * cosf(4.0f * hr - 63.0f * DEG2RAD);

    float Lm50 = Lbar - 50.0f;
    float Lm50sq = Lm50 * Lm50;
    float Sl = 1.0f + 0.015f * Lm50sq / sqrtf(20.0f + Lm50sq);
    float Sc = 1.0f + 0.045f * Cbarp;
    float Sh = 1.0f + 0.015f * Cbarp * T;
    float t275 = (hbar - 275.0f) * (1.0f / 25.0f);
    float dtheta = 30.0f * expf(-(t275 * t275));
    float cb7 = pow7f(Cbarp);
    float Rc = 2.0f * sqrtf(cb7 / (cb7 + P25_7));
    float Rt = -Rc * sinf(2.0f * dtheta * DEG2RAD);

    float tL = dLp / Sl;
    float tC = dCp / Sc;
    float tH = dHp / Sh;
    float s = tL * tL + tC * tC + tH * tH + Rt * tC * tH;
    return sqrtf(fmaxf(s, 0.0f));
}

// Each thread processes 4 pixels = 12 floats = 3 float4 loads per image.
__global__ __launch_bounds__(256) void de_main(const float4* __restrict__ gen,
                                               const float4* __restrict__ gt,
                                               float* __restrict__ partial,
                                               int ntrip) {
    int tid = blockIdx.x * blockDim.x + threadIdx.x;
    int stride = gridDim.x * blockDim.x;
    float acc = 0.0f;

    for (int t = tid; t < ntrip; t += stride) {
        float4 g0 = gen[3 * t + 0], g1 = gen[3 * t + 1], g2 = gen[3 * t + 2];
        float4 r0 = gt [3 * t + 0], r1 = gt [3 * t + 1], r2 = gt [3 * t + 2];
        float ge[12] = {g0.x, g0.y, g0.z, g0.w, g1.x, g1.y, g1.z, g1.w,
                        g2.x, g2.y, g2.z, g2.w};
        float rt[12] = {r0.x, r0.y, r0.z, r0.w, r1.x, r1.y, r1.z, r1.w,
                        r2.x, r2.y, r2.z, r2.w};
        #pragma unroll
        for (int p = 0; p < 4; ++p) {
            float L1, A1, B1, L2, A2, B2;
            rgb2lab(rt[3 * p + 0], rt[3 * p + 1], rt[3 * p + 2], L1, A1, B1); // gt
            rgb2lab(ge[3 * p + 0], ge[3 * p + 1], ge[3 * p + 2], L2, A2, B2); // gen
            acc += fabsf(ciede2000(L1, A1, B1, L2, A2, B2));
        }
    }

    // wave64 reduce, then cross-wave via LDS
    for (int off = 32; off > 0; off >>= 1) acc += __shfl_down(acc, off, 64);
    __shared__ float sm[4];
    int lane = threadIdx.x & 63;
    int wid  = threadIdx.x >> 6;
    if (lane == 0) sm[wid] = acc;
    __syncthreads();
    if (threadIdx.x == 0) partial[blockIdx.x] = sm[0] + sm[1] + sm[2] + sm[3];
}

__global__ __launch_bounds__(256) void de_final(const float* __restrict__ partial,
                                                float* __restrict__ out,
                                                int n, float inv_npix) {
    float acc = 0.0f;
    for (int i = threadIdx.x; i < n; i += 256) acc += partial[i];
    for (int off = 32; off > 0; off >>= 1) acc += __shfl_down(acc, off, 64);
    __shared__ float sm[4];
    int lane = threadIdx.x & 63;
    int wid  = threadIdx.x >> 6;
    if (lane == 0) sm[wid] = acc;
    __syncthreads();
    if (threadIdx.x == 0) out[0] = (sm[0] + sm[1] + sm[2] + sm[3]) * inv_npix;
}

extern "C" void kernel_launch(void* const* d_in, const int* in_sizes, int n_in,
                              void* d_out, int out_size, void* d_ws, size_t ws_size,
                              hipStream_t stream) {
    const float4* gen = (const float4*)d_in[0];  // genImage
    const float4* gt  = (const float4*)d_in[1];  // gtImage

    const int total_f = in_sizes[0];         // 25,165,824 floats
    const int ntrip   = total_f / 12;        // 4-pixel work items (exact)
    const int npix    = total_f / 3;         // 8,388,608 pixels

    float* partial = (float*)d_ws;           // 2048 floats of scratch
    const int blocks = 2048;

    de_main<<<blocks, 256, 0, stream>>>(gen, gt, partial, ntrip);
    de_final<<<1, 256, 0, stream>>>(partial, (float*)d_out,
                                    blocks, 1.0f / (float)npix);
}

// Round 2
// 82.115 us; speedup vs baseline: 3.8375x; 3.8375x over previous
//
#include <hip/hip_runtime.h>

// deltaE (CIEDE2000) color loss: mean over 32x512x512 pixels.
// Reference reshapes (B,3,H,W)->(B,H,W,3) WITHOUT transpose, so each pixel's
// RGB is 3 consecutive floats in the flat array.
//
// All transcendentals use single-instruction HW approx (v_log/v_exp/v_sin/
// v_cos/v_rcp/v_rsq/v_sqrt, ~1 ulp) — hue math is carried in REVOLUTIONS so
// v_sin/v_cos apply natively and deg<->rad conversion disappears.

__device__ __forceinline__ float fexp2(float x) { return __builtin_amdgcn_exp2f(x); }
__device__ __forceinline__ float flog2(float x) { return __builtin_amdgcn_logf(x); }
__device__ __forceinline__ float frcp(float x)  { return __builtin_amdgcn_rcpf(x); }
__device__ __forceinline__ float fsqrt_(float x){ return __builtin_amdgcn_sqrtf(x); }
__device__ __forceinline__ float frsq(float x)  { return __builtin_amdgcn_rsqf(x); }
// sin/cos of (2*pi*x): input in revolutions; fract-reduce for HW range safety.
__device__ __forceinline__ float cos_rev(float x) {
    x = x - floorf(x);
    return __builtin_amdgcn_cosf(x);
}
__device__ __forceinline__ float sin_rev(float x) {
    x = x - floorf(x);
    return __builtin_amdgcn_sinf(x);
}

__device__ __forceinline__ float pow7f(float x) {
    float x2 = x * x;
    float x3 = x2 * x;
    return x3 * x3 * x;
}

// atan2 returning REVOLUTIONS in (-0.5, 0.5]. Cephes-style: reduce to
// [0, tan(pi/8)] then degree-9 odd minimax polynomial (~1e-7 rad).
__device__ __forceinline__ float atan2_rev(float y, float x) {
    float ax = fabsf(x), ay = fabsf(y);
    float mx = fmaxf(ax, ay), mn = fminf(ax, ay);
    float a = mn * frcp(mx);
    if (mx == 0.0f) a = 0.0f;                  // atan2(0,0) -> 0
    bool big = a > 0.41421356f;
    float z = big ? (a - 1.0f) * frcp(a + 1.0f) : a;   // z in [-0.293, 0.414]
    float s = z * z;
    float p = fmaf(fmaf(fmaf(fmaf(8.05374449538e-2f, s, -1.38776856032e-1f),
                             s, 1.99777106478e-1f),
                        s, -3.33329491539e-1f),
                   s * z, z);
    if (big) p += 0.7853981633974483f;          // + pi/4
    float r = p * 0.15915494309189535f;         // rad -> rev
    if (ay > ax) r = 0.25f - r;                 // reflect across pi/4
    if (x < 0.0f) r = 0.5f - r;                 // second quadrant
    return (y < 0.0f) ? -r : r;
}

__device__ __forceinline__ float srgb_lin(float v) {
    // both paths computed, select (wave64-friendly); arg of log2 >= 0.0521
    float p = fexp2(2.4f * flog2((v + 0.055f) * (1.0f / 1.055f)));
    return (v <= 0.04045f) ? v * (1.0f / 12.92f) : p;
}

__device__ __forceinline__ float fxyz(float t) {
    // t >= 0; log2(0) = -inf -> exp2 -> 0, never selected (0 < 0.008856)
    float c = fexp2(0.3333333333333333f * flog2(t));
    return (t > 0.008856f) ? c : fmaf(7.787f, t, 16.0f / 116.0f);
}

__device__ __forceinline__ void rgb2lab(float r, float g, float b,
                                        float& L, float& A, float& B) {
    float rl = srgb_lin(r), gl = srgb_lin(g), bl = srgb_lin(b);
    float x = (0.412453f * rl + 0.357580f * gl + 0.180423f * bl) * (1.0f / 0.95047f);
    float y = (0.212671f * rl + 0.715160f * gl + 0.072169f * bl);
    float z = (0.019334f * rl + 0.119193f * gl + 0.950227f * bl) * (1.0f / 1.08883f);
    float fx = fxyz(x), fy = fxyz(y), fz = fxyz(z);
    L = fmaf(116.0f, fy, -16.0f);
    A = 500.0f * (fx - fy);
    B = 200.0f * (fy - fz);
}

__device__ __forceinline__ float ciede2000(float L1, float a1, float b1,
                                           float L2, float a2, float b2) {
    const float P25_7 = 6103515625.0f;          // 25^7

    float C1 = fsqrt_(fmaf(a1, a1, b1 * b1));
    float C2 = fsqrt_(fmaf(a2, a2, b2 * b2));
    float Cbar = 0.5f * (C1 + C2);
    float c7 = pow7f(Cbar);
    float G = 0.5f - 0.5f * fsqrt_(c7 * frcp(c7 + P25_7));
    float a1p = fmaf(a1, G, a1);                // a1*(1+G)
    float a2p = fmaf(a2, G, a2);
    float C1p = fsqrt_(fmaf(a1p, a1p, b1 * b1));
    float C2p = fsqrt_(fmaf(a2p, a2p, b2 * b2));

    // hue in revolutions, [0,1)
    float h1 = atan2_rev(b1, a1p); if (h1 < 0.0f) h1 += 1.0f;
    float h2 = atan2_rev(b2, a2p); if (h2 < 0.0f) h2 += 1.0f;

    float dLp = L2 - L1;
    float dCp = C2p - C1p;
    float CC  = C1p * C2p;
    // CC==0 special cases of the reference are numerically no-ops:
    // dHp = 2*sqrt(0)*sin = 0 => tH = 0 kills every hbar-dependent term.
    float hd = h2 - h1;
    float dh = (hd > 0.5f) ? hd - 1.0f : ((hd < -0.5f) ? hd + 1.0f : hd);
    float dHp = 2.0f * fsqrt_(CC) * sin_rev(0.5f * dh);

    float Lbar  = 0.5f * (L1 + L2);
    float Cbarp = 0.5f * (C1p + C2p);
    float hsum  = h1 + h2;
    float hbar  = (fabsf(h1 - h2) <= 0.5f) ? 0.5f * hsum
                : ((hsum < 1.0f) ? 0.5f * hsum + 0.5f : 0.5f * hsum - 0.5f);

    float T = 1.0f
            - 0.17f * cos_rev(hbar - 0.08333333333f)        // -30deg
            + 0.24f * cos_rev(hbar + hbar)
            + 0.32f * cos_rev(fmaf(3.0f, hbar, 0.01666666667f))  // +6deg
            - 0.20f * cos_rev(fmaf(4.0f, hbar, -0.175f));        // -63deg

    float Lm50 = Lbar - 50.0f;
    float q = Lm50 * Lm50;
    float Sl = fmaf(0.015f * q, frsq(20.0f + q), 1.0f);
    float Sc = fmaf(0.045f, Cbarp, 1.0f);
    float Sh = fmaf(0.015f * Cbarp, T, 1.0f);

    float td = (hbar - 0.76388888889f) * 14.4f;  // (hbar*360 - 275)/25
    float dtheta = 30.0f * fexp2(-1.4426950408889634f * td * td);
    float cb7 = pow7f(Cbarp);
    float Rc = 2.0f * fsqrt_(cb7 * frcp(cb7 + P25_7));
    float Rt = -Rc * sin_rev(dtheta * (1.0f / 180.0f));  // sin(2*dtheta deg)

    float tL = dLp * frcp(Sl);
    float tC = dCp * frcp(Sc);
    float tH = dHp * frcp(Sh);
    float s = fmaf(tL, tL, fmaf(tC, tC, fmaf(tH, tH, Rt * tC * tH)));
    return fsqrt_(fmaxf(s, 0.0f));
}

// Each thread processes 4 pixels = 12 floats = 3 float4 loads per image.
__global__ __launch_bounds__(256) void de_main(const float4* __restrict__ gen,
                                               const float4* __restrict__ gt,
                                               float* __restrict__ partial,
                                               int ntrip) {
    int tid = blockIdx.x * blockDim.x + threadIdx.x;
    int stride = gridDim.x * blockDim.x;
    float acc = 0.0f;

    for (int t = tid; t < ntrip; t += stride) {
        float4 g0 = gen[3 * t + 0], g1 = gen[3 * t + 1], g2 = gen[3 * t + 2];
        float4 r0 = gt [3 * t + 0], r1 = gt [3 * t + 1], r2 = gt [3 * t + 2];
        float ge[12] = {g0.x, g0.y, g0.z, g0.w, g1.x, g1.y, g1.z, g1.w,
                        g2.x, g2.y, g2.z, g2.w};
        float rt[12] = {r0.x, r0.y, r0.z, r0.w, r1.x, r1.y, r1.z, r1.w,
                        r2.x, r2.y, r2.z, r2.w};
        #pragma unroll
        for (int p = 0; p < 4; ++p) {
            float L1, A1, B1, L2, A2, B2;
            rgb2lab(rt[3 * p + 0], rt[3 * p + 1], rt[3 * p + 2], L1, A1, B1); // gt
            rgb2lab(ge[3 * p + 0], ge[3 * p + 1], ge[3 * p + 2], L2, A2, B2); // gen
            acc += fabsf(ciede2000(L1, A1, B1, L2, A2, B2));
        }
    }

    for (int off = 32; off > 0; off >>= 1) acc += __shfl_down(acc, off, 64);
    __shared__ float sm[4];
    int lane = threadIdx.x & 63;
    int wid  = threadIdx.x >> 6;
    if (lane == 0) sm[wid] = acc;
    __syncthreads();
    if (threadIdx.x == 0) partial[blockIdx.x] = sm[0] + sm[1] + sm[2] + sm[3];
}

__global__ __launch_bounds__(256) void de_final(const float* __restrict__ partial,
                                                float* __restrict__ out,
                                                int n, float inv_npix) {
    float acc = 0.0f;
    for (int i = threadIdx.x; i < n; i += 256) acc += partial[i];
    for (int off = 32; off > 0; off >>= 1) acc += __shfl_down(acc, off, 64);
    __shared__ float sm[4];
    int lane = threadIdx.x & 63;
    int wid  = threadIdx.x >> 6;
    if (lane == 0) sm[wid] = acc;
    __syncthreads();
    if (threadIdx.x == 0) out[0] = (sm[0] + sm[1] + sm[2] + sm[3]) * inv_npix;
}

extern "C" void kernel_launch(void* const* d_in, const int* in_sizes, int n_in,
                              void* d_out, int out_size, void* d_ws, size_t ws_size,
                              hipStream_t stream) {
    const float4* gen = (const float4*)d_in[0];  // genImage
    const float4* gt  = (const float4*)d_in[1];  // gtImage

    const int total_f = in_sizes[0];             // 25,165,824 floats
    const int ntrip   = total_f / 12;            // 4-pixel work items (exact)
    const int npix    = total_f / 3;             // 8,388,608 pixels

    float* partial = (float*)d_ws;
    const int blocks = 2048;

    de_main<<<blocks, 256, 0, stream>>>(gen, gt, partial, ntrip);
    de_final<<<1, 256, 0, stream>>>(partial, (float*)d_out,
                                    blocks, 1.0f / (float)npix);
}

// Round 3
// 74.733 us; speedup vs baseline: 4.2165x; 1.0988x over previous
//
#include <hip/hip_runtime.h>

// deltaE (CIEDE2000) color loss: mean over 32x512x512 pixels.
// Reference reshapes (B,3,H,W)->(B,H,W,3) WITHOUT transpose => each pixel's
// RGB is 3 consecutive floats. 4 px/thread = 3 float4 loads per image.
//
// All transcendentals are single-instruction HW approx; hue math in
// REVOLUTIONS (v_sin/v_cos native). Exact-trip kernel + 1-deep register
// prefetch to hide HBM latency (round-2 showed VALUBusy 72% from exposed
// load latency at VGPR=36).

__device__ __forceinline__ float fexp2(float x) { return __builtin_amdgcn_exp2f(x); }
__device__ __forceinline__ float flog2(float x) { return __builtin_amdgcn_logf(x); }
__device__ __forceinline__ float frcp(float x)  { return __builtin_amdgcn_rcpf(x); }
__device__ __forceinline__ float fsqrt_(float x){ return __builtin_amdgcn_sqrtf(x); }
__device__ __forceinline__ float frsq(float x)  { return __builtin_amdgcn_rsqf(x); }
__device__ __forceinline__ float ffract(float x){ return __builtin_amdgcn_fractf(x); }
// sin/cos of (2*pi*x), x in revolutions; v_fract reduction (single instr).
__device__ __forceinline__ float cos_rev(float x) { return __builtin_amdgcn_cosf(ffract(x)); }
__device__ __forceinline__ float sin_rev(float x) { return __builtin_amdgcn_sinf(ffract(x)); }

__device__ __forceinline__ float pow7f(float x) {
    float x2 = x * x;
    float x3 = x2 * x;
    return x3 * x3 * x;
}

// atan2 in REVOLUTIONS, (-0.5, 0.5]. Single reduction to a=mn/mx in [0,1],
// degree-11 odd minimax (~1e-5 rad), then octant fixups as selects.
__device__ __forceinline__ float atan2_rev(float y, float x) {
    float ax = fabsf(x), ay = fabsf(y);
    float mx = fmaxf(ax, ay), mn = fminf(ax, ay);
    float a = mn * frcp(mx);
    if (mx == 0.0f) a = 0.0f;                 // atan2(0,0) -> 0
    float s = a * a;
    float p = fmaf(s, fmaf(s, fmaf(s, fmaf(s, fmaf(s,
              -1.1721200e-2f, 5.2653320e-2f), -1.1643287e-1f),
               1.9354346e-1f), -3.3262347e-1f), 9.9997726e-1f);
    float r = a * p * 0.15915494309189535f;   // rad -> rev, in [0, 0.125]
    if (ay > ax) r = 0.25f - r;
    if (x < 0.0f) r = 0.5f - r;
    if (y < 0.0f) r = -r;
    return r;
}

__device__ __forceinline__ float srgb_lin(float v) {
    float p = fexp2(2.4f * flog2((v + 0.055f) * (1.0f / 1.055f)));
    return (v <= 0.04045f) ? v * (1.0f / 12.92f) : p;
}

__device__ __forceinline__ float fxyz(float t) {
    float c = fexp2(0.3333333333333333f * flog2(t));
    return (t > 0.008856f) ? c : fmaf(7.787f, t, 16.0f / 116.0f);
}

__device__ __forceinline__ void rgb2lab(float r, float g, float b,
                                        float& L, float& A, float& B) {
    float rl = srgb_lin(r), gl = srgb_lin(g), bl = srgb_lin(b);
    float x = (0.412453f * rl + 0.357580f * gl + 0.180423f * bl) * (1.0f / 0.95047f);
    float y = (0.212671f * rl + 0.715160f * gl + 0.072169f * bl);
    float z = (0.019334f * rl + 0.119193f * gl + 0.950227f * bl) * (1.0f / 1.08883f);
    float fx = fxyz(x), fy = fxyz(y), fz = fxyz(z);
    L = fmaf(116.0f, fy, -16.0f);
    A = 500.0f * (fx - fy);
    B = 200.0f * (fy - fz);
}

__device__ __forceinline__ float ciede2000(float L1, float a1, float b1,
                                           float L2, float a2, float b2) {
    const float P25_7 = 6103515625.0f;        // 25^7

    float C1 = fsqrt_(fmaf(a1, a1, b1 * b1));
    float C2 = fsqrt_(fmaf(a2, a2, b2 * b2));
    float Cbar = 0.5f * (C1 + C2);
    float c7 = pow7f(Cbar);
    float G = 0.5f - 0.5f * fsqrt_(c7 * frcp(c7 + P25_7));
    float a1p = fmaf(a1, G, a1);
    float a2p = fmaf(a2, G, a2);
    float C1p = fsqrt_(fmaf(a1p, a1p, b1 * b1));
    float C2p = fsqrt_(fmaf(a2p, a2p, b2 * b2));

    float h1 = atan2_rev(b1, a1p); if (h1 < 0.0f) h1 += 1.0f;
    float h2 = atan2_rev(b2, a2p); if (h2 < 0.0f) h2 += 1.0f;

    float dLp = L2 - L1;
    float dCp = C2p - C1p;
    float CC  = C1p * C2p;
    // Reference's CC==0 specials are numeric no-ops: dHp=0 => tH=0.
    float hd = h2 - h1;
    float dh = (hd > 0.5f) ? hd - 1.0f : ((hd < -0.5f) ? hd + 1.0f : hd);
    float dHp = 2.0f * fsqrt_(CC) * sin_rev(0.5f * dh);

    float Lbar  = 0.5f * (L1 + L2);
    float Cbarp = 0.5f * (C1p + C2p);
    float hsum  = h1 + h2;
    float hbar  = (fabsf(h1 - h2) <= 0.5f) ? 0.5f * hsum
                : ((hsum < 1.0f) ? 0.5f * hsum + 0.5f : 0.5f * hsum - 0.5f);

    float T = 1.0f
            - 0.17f * cos_rev(hbar - 0.08333333333f)             // -30deg
            + 0.24f * cos_rev(hbar + hbar)
            + 0.32f * cos_rev(fmaf(3.0f, hbar, 0.01666666667f))  // +6deg
            - 0.20f * cos_rev(fmaf(4.0f, hbar, -0.175f));        // -63deg

    float Lm50 = Lbar - 50.0f;
    float q = Lm50 * Lm50;
    float Sl = fmaf(0.015f * q, frsq(20.0f + q), 1.0f);
    float Sc = fmaf(0.045f, Cbarp, 1.0f);
    float Sh = fmaf(0.015f * Cbarp, T, 1.0f);

    float td = (hbar - 0.76388888889f) * 14.4f;   // (hbar*360 - 275)/25
    float dtheta = 30.0f * fexp2(-1.4426950408889634f * td * td);
    float cb7 = pow7f(Cbarp);
    float Rc = 2.0f * fsqrt_(cb7 * frcp(cb7 + P25_7));
    float Rt = -Rc * sin_rev(dtheta * (1.0f / 180.0f));  // sin(2*dtheta deg)

    // one rcp instead of three
    float ScSh = Sc * Sh, SlSh = Sl * Sh, SlSc = Sl * Sc;
    float R3 = frcp(Sl * ScSh);
    float tL = dLp * ScSh * R3;
    float tC = dCp * SlSh * R3;
    float tH = dHp * SlSc * R3;
    float s = fmaf(tL, tL, fmaf(tC, tC, fmaf(tH, tH, Rt * tC * tH)));
    return fsqrt_(fmaxf(s, 0.0f));
}

__device__ __forceinline__ void process4(const float4& g0, const float4& g1,
                                         const float4& g2, const float4& r0,
                                         const float4& r1, const float4& r2,
                                         float& acc) {
    const float ge[12] = {g0.x, g0.y, g0.z, g0.w, g1.x, g1.y, g1.z, g1.w,
                          g2.x, g2.y, g2.z, g2.w};
    const float rt[12] = {r0.x, r0.y, r0.z, r0.w, r1.x, r1.y, r1.z, r1.w,
                          r2.x, r2.y, r2.z, r2.w};
    #pragma unroll
    for (int p = 0; p < 4; ++p) {
        float L1, A1, B1, L2, A2, B2;
        rgb2lab(rt[3 * p + 0], rt[3 * p + 1], rt[3 * p + 2], L1, A1, B1); // gt
        rgb2lab(ge[3 * p + 0], ge[3 * p + 1], ge[3 * p + 2], L2, A2, B2); // gen
        acc += fabsf(ciede2000(L1, A1, B1, L2, A2, B2));
    }
}

__device__ __forceinline__ void block_reduce_store(float acc, float* dst) {
    for (int off = 32; off > 0; off >>= 1) acc += __shfl_down(acc, off, 64);
    __shared__ float sm[4];
    int lane = threadIdx.x & 63;
    int wid  = threadIdx.x >> 6;
    if (lane == 0) sm[wid] = acc;
    __syncthreads();
    if (threadIdx.x == 0) *dst = sm[0] + sm[1] + sm[2] + sm[3];
}

// Exact-trip kernel: every thread does exactly NITER 4-pixel items.
// 1-deep register prefetch; last iteration peeled (no OOB prefetch).
template <int NITER>
__global__ __launch_bounds__(256) void de_main_fix(const float4* __restrict__ gen,
                                                   const float4* __restrict__ gt,
                                                   float* __restrict__ partial,
                                                   int stride) {
    int t = blockIdx.x * 256 + threadIdx.x;
    float acc = 0.0f;

    float4 cg0 = gen[3 * t + 0], cg1 = gen[3 * t + 1], cg2 = gen[3 * t + 2];
    float4 cr0 = gt [3 * t + 0], cr1 = gt [3 * t + 1], cr2 = gt [3 * t + 2];

    #pragma unroll 1
    for (int it = 0; it < NITER - 1; ++it) {
        int tn = t + stride;
        float4 ng0 = gen[3 * tn + 0], ng1 = gen[3 * tn + 1], ng2 = gen[3 * tn + 2];
        float4 nr0 = gt [3 * tn + 0], nr1 = gt [3 * tn + 1], nr2 = gt [3 * tn + 2];
        process4(cg0, cg1, cg2, cr0, cr1, cr2, acc);
        cg0 = ng0; cg1 = ng1; cg2 = ng2;
        cr0 = nr0; cr1 = nr1; cr2 = nr2;
        t = tn;
    }
    process4(cg0, cg1, cg2, cr0, cr1, cr2, acc);

    block_reduce_store(acc, &partial[blockIdx.x]);
}

// Generic fallback (bounds-checked grid-stride), used only if sizes change.
__global__ __launch_bounds__(256) void de_main_gen(const float4* __restrict__ gen,
                                                   const float4* __restrict__ gt,
                                                   float* __restrict__ partial,
                                                   int ntrip) {
    int tid = blockIdx.x * blockDim.x + threadIdx.x;
    int stride = gridDim.x * blockDim.x;
    float acc = 0.0f;
    for (int t = tid; t < ntrip; t += stride) {
        float4 g0 = gen[3 * t + 0], g1 = gen[3 * t + 1], g2 = gen[3 * t + 2];
        float4 r0 = gt [3 * t + 0], r1 = gt [3 * t + 1], r2 = gt [3 * t + 2];
        process4(g0, g1, g2, r0, r1, r2, acc);
    }
    block_reduce_store(acc, &partial[blockIdx.x]);
}

__global__ __launch_bounds__(256) void de_final(const float* __restrict__ partial,
                                                float* __restrict__ out,
                                                int n, float inv_npix) {
    float acc = 0.0f;
    for (int i = threadIdx.x; i < n; i += 256) acc += partial[i];
    for (int off = 32; off > 0; off >>= 1) acc += __shfl_down(acc, off, 64);
    __shared__ float sm[4];
    int lane = threadIdx.x & 63;
    int wid  = threadIdx.x >> 6;
    if (lane == 0) sm[wid] = acc;
    __syncthreads();
    if (threadIdx.x == 0) out[0] = (sm[0] + sm[1] + sm[2] + sm[3]) * inv_npix;
}

extern "C" void kernel_launch(void* const* d_in, const int* in_sizes, int n_in,
                              void* d_out, int out_size, void* d_ws, size_t ws_size,
                              hipStream_t stream) {
    const float4* gen = (const float4*)d_in[0];  // genImage
    const float4* gt  = (const float4*)d_in[1];  // gtImage

    const int total_f = in_sizes[0];             // 25,165,824 floats
    const int ntrip   = total_f / 12;            // 4-pixel work items
    const int npix    = total_f / 3;

    float* partial = (float*)d_ws;
    const int blocks  = 2048;
    const int threads = blocks * 256;

    if (ntrip == threads * 4) {
        de_main_fix<4><<<blocks, 256, 0, stream>>>(gen, gt, partial, threads);
    } else {
        de_main_gen<<<blocks, 256, 0, stream>>>(gen, gt, partial, ntrip);
    }
    de_final<<<1, 256, 0, stream>>>(partial, (float*)d_out,
                                    blocks, 1.0f / (float)npix);
}

// Round 4
// 71.651 us; speedup vs baseline: 4.3979x; 1.0430x over previous
//
#include <hip/hip_runtime.h>

// deltaE (CIEDE2000) color loss: mean over 32x512x512 pixels.
// Reference reshapes (B,3,H,W)->(B,H,W,3) WITHOUT transpose => each pixel's
// RGB is 3 consecutive floats. 4 px/thread = 3 float4 loads per image.
//
// Round-4: (1) __launch_bounds__(256,4) -> 128-VGPR budget so the 4-pixel
// ILP and 1-deep prefetch survive regalloc (round-3 compiled to VGPR=32 and
// rematerialized everything, VALUBusy 75% with 2x the dataflow's instrs).
// (2) hue math algebraized: dHp/T/hbar-direction from vector identities,
// only ONE atan2 (for the dtheta Gaussian) and ONE sin remain per pixel.

__device__ __forceinline__ float fexp2(float x) { return __builtin_amdgcn_exp2f(x); }
__device__ __forceinline__ float flog2(float x) { return __builtin_amdgcn_logf(x); }
__device__ __forceinline__ float frcp(float x)  { return __builtin_amdgcn_rcpf(x); }
__device__ __forceinline__ float fsqrt_(float x){ return __builtin_amdgcn_sqrtf(x); }
__device__ __forceinline__ float frsq(float x)  { return __builtin_amdgcn_rsqf(x); }
__device__ __forceinline__ float ffract(float x){ return __builtin_amdgcn_fractf(x); }
__device__ __forceinline__ float sin_rev(float x) { return __builtin_amdgcn_sinf(ffract(x)); }

__device__ __forceinline__ float pow7f(float x) {
    float x2 = x * x;
    float x3 = x2 * x;
    return x3 * x3 * x;
}

// atan2 in REVOLUTIONS, (-0.5, 0.5]. Reduce to a=mn/mx in [0,1], degree-11
// odd minimax (~1e-5 rad), octant fixups as selects.
__device__ __forceinline__ float atan2_rev(float y, float x) {
    float ax = fabsf(x), ay = fabsf(y);
    float mx = fmaxf(ax, ay), mn = fminf(ax, ay);
    float a = mn * frcp(mx);
    if (mx == 0.0f) a = 0.0f;                 // atan2(0,0) -> 0
    float s = a * a;
    float p = fmaf(s, fmaf(s, fmaf(s, fmaf(s, fmaf(s,
              -1.1721200e-2f, 5.2653320e-2f), -1.1643287e-1f),
               1.9354346e-1f), -3.3262347e-1f), 9.9997726e-1f);
    float r = a * p * 0.15915494309189535f;   // rad -> rev
    if (ay > ax) r = 0.25f - r;
    if (x < 0.0f) r = 0.5f - r;
    if (y < 0.0f) r = -r;
    return r;
}

__device__ __forceinline__ float srgb_lin(float v) {
    float p = fexp2(2.4f * flog2((v + 0.055f) * (1.0f / 1.055f)));
    return (v <= 0.04045f) ? v * (1.0f / 12.92f) : p;
}

__device__ __forceinline__ float fxyz(float t) {
    float c = fexp2(0.3333333333333333f * flog2(t));
    return (t > 0.008856f) ? c : fmaf(7.787f, t, 16.0f / 116.0f);
}

__device__ __forceinline__ void rgb2lab(float r, float g, float b,
                                        float& L, float& A, float& B) {
    float rl = srgb_lin(r), gl = srgb_lin(g), bl = srgb_lin(b);
    // white point folded into matrix rows (x/0.95047, z/1.08883)
    float x = fmaf(0.43395296f, rl, fmaf(0.37621626f, gl, 0.18982646f * bl));
    float y = fmaf(0.212671f,  rl, fmaf(0.715160f,  gl, 0.072169f  * bl));
    float z = fmaf(0.017757f,  rl, fmaf(0.10946953f, gl, 0.87271810f * bl));
    float fx = fxyz(x), fy = fxyz(y), fz = fxyz(z);
    L = fmaf(116.0f, fy, -16.0f);
    A = 500.0f * (fx - fy);
    B = 200.0f * (fy - fz);
}

__device__ __forceinline__ float ciede2000(float L1, float a1, float b1,
                                           float L2, float a2, float b2) {
    const float P25_7 = 6103515625.0f;        // 25^7

    float b1sq = b1 * b1, b2sq = b2 * b2;
    float C1 = fsqrt_(fmaf(a1, a1, b1sq));
    float C2 = fsqrt_(fmaf(a2, a2, b2sq));
    float Cbar = 0.5f * (C1 + C2);
    float c7 = pow7f(Cbar);
    float G1 = 1.5f - 0.5f * fsqrt_(c7 * frcp(c7 + P25_7));   // 1+G
    float a1p = a1 * G1;
    float a2p = a2 * G1;
    float C1p = fsqrt_(fmaf(a1p, a1p, b1sq));
    float C2p = fsqrt_(fmaf(a2p, a2p, b2sq));
    float CC  = C1p * C2p;

    // dHp = 2*sqrt(CC)*sin(dh/2) = sign(sin(h2-h1)) * sqrt(2*(CC - dot)):
    //   dot  = cos(h2-h1)*CC = a1p*a2p + b1*b2
    //   cross= sin(h2-h1)*CC = b2*a1p - a2p*b1
    float dot   = fmaf(a1p, a2p, b1 * b2);
    float cross = fmaf(b2, a1p, -a2p * b1);
    float dHp = copysignf(fsqrt_(fmaxf(2.0f * (CC - dot), 0.0f)), cross);

    float dLp = L2 - L1;
    float dCp = C2p - C1p;

    // hbar bisector direction = normalize(u1+u2), ui=(aip,bi)/Cip; scale by
    // CC>0: matches the reference's 3-branch hbar for every CC!=0 case.
    float sx = fmaf(a1p, C2p, a2p * C1p);
    float sy = fmaf(b1,  C2p, b2  * C1p);
    float n2 = fmaf(sx, sx, sy * sy);
    float inv = (n2 > 0.0f) ? frsq(n2) : 0.0f;   // degenerate: tH=0 anyway
    float ch = sx * inv, sh = sy * inv;          // cos(hbar), sin(hbar)

    // T by angle addition — no trig
    float c2 = fmaf(2.0f * ch, ch, -1.0f);
    float s2 = 2.0f * sh * ch;
    float c3 = fmaf(c2, ch, -s2 * sh);
    float s3 = fmaf(s2, ch,  c2 * sh);
    float c4 = fmaf(2.0f * c2, c2, -1.0f);
    float s4 = 2.0f * s2 * c2;
    float T = 1.0f
            - 0.17f * fmaf(ch, 0.8660254037844387f, sh * 0.5f)             // cos(h-30)
            + 0.24f * c2
            + 0.32f * fmaf(c3, 0.9945218953682733f, -s3 * 0.10452846326765347f)  // cos(3h+6)
            - 0.20f * fmaf(c4, 0.45399049973954675f, s4 * 0.8910065241883679f);  // cos(4h-63)

    // angle itself only for the 275-degree Gaussian
    float hbar = atan2_rev(sy, sx);
    if (hbar < 0.0f) hbar += 1.0f;               // [0,1) revolutions

    float Lbar  = 0.5f * (L1 + L2);
    float Cbarp = 0.5f * (C1p + C2p);
    float Lm50 = Lbar - 50.0f;
    float q = Lm50 * Lm50;
    float Sl = fmaf(0.015f * q, frsq(20.0f + q), 1.0f);
    float Sc = fmaf(0.045f, Cbarp, 1.0f);
    float Sh = fmaf(0.015f * Cbarp, T, 1.0f);

    float td = fmaf(hbar, 14.4f, -11.0f);        // (360*hbar - 275)/25
    float dtheta = 30.0f * fexp2(-1.4426950408889634f * td * td);
    float cb7 = pow7f(Cbarp);
    float Rc = 2.0f * fsqrt_(cb7 * frcp(cb7 + P25_7));
    float Rt = -Rc * sin_rev(dtheta * (1.0f / 180.0f));  // sin(2*dtheta deg)

    float ScSh = Sc * Sh;
    float R3 = frcp(Sl * ScSh);
    float tL = dLp * ScSh * R3;
    float tC = dCp * (Sl * Sh) * R3;
    float tH = dHp * (Sl * Sc) * R3;
    float s = fmaf(tL, tL, fmaf(tC, tC, fmaf(tH, tH, Rt * tC * tH)));
    return fsqrt_(fmaxf(s, 0.0f));
}

__device__ __forceinline__ float de_px(float gr, float gg, float gb,
                                       float rr, float rg, float rb) {
    float L1, A1, B1, L2, A2, B2;
    rgb2lab(rr, rg, rb, L1, A1, B1);   // gt
    rgb2lab(gr, gg, gb, L2, A2, B2);   // gen
    return fabsf(ciede2000(L1, A1, B1, L2, A2, B2));
}

// 4 pixels from 3 float4s each, named components (no arrays -> no scratch).
__device__ __forceinline__ void process4(const float4& g0, const float4& g1,
                                         const float4& g2, const float4& r0,
                                         const float4& r1, const float4& r2,
                                         float& acc) {
    acc += de_px(g0.x, g0.y, g0.z, r0.x, r0.y, r0.z);
    acc += de_px(g0.w, g1.x, g1.y, r0.w, r1.x, r1.y);
    acc += de_px(g1.z, g1.w, g2.x, r1.z, r1.w, r2.x);
    acc += de_px(g2.y, g2.z, g2.w, r2.y, r2.z, r2.w);
}

__device__ __forceinline__ void block_reduce_store(float acc, float* dst) {
    for (int off = 32; off > 0; off >>= 1) acc += __shfl_down(acc, off, 64);
    __shared__ float sm[4];
    int lane = threadIdx.x & 63;
    int wid  = threadIdx.x >> 6;
    if (lane == 0) sm[wid] = acc;
    __syncthreads();
    if (threadIdx.x == 0) *dst = sm[0] + sm[1] + sm[2] + sm[3];
}

// Exact-trip kernel, 1-deep register prefetch, loads pinned early.
template <int NITER>
__global__ __launch_bounds__(256, 4) void de_main_fix(const float4* __restrict__ gen,
                                                      const float4* __restrict__ gt,
                                                      float* __restrict__ partial,
                                                      int stride) {
    int t = blockIdx.x * 256 + threadIdx.x;
    float acc = 0.0f;

    float4 cg0 = gen[3 * t + 0], cg1 = gen[3 * t + 1], cg2 = gen[3 * t + 2];
    float4 cr0 = gt [3 * t + 0], cr1 = gt [3 * t + 1], cr2 = gt [3 * t + 2];

    #pragma unroll 1
    for (int it = 0; it < NITER - 1; ++it) {
        int tn = t + stride;
        float4 ng0 = gen[3 * tn + 0], ng1 = gen[3 * tn + 1], ng2 = gen[3 * tn + 2];
        float4 nr0 = gt [3 * tn + 0], nr1 = gt [3 * tn + 1], nr2 = gt [3 * tn + 2];
        __builtin_amdgcn_sched_barrier(0);   // keep prefetch issued before compute
        process4(cg0, cg1, cg2, cr0, cr1, cr2, acc);
        cg0 = ng0; cg1 = ng1; cg2 = ng2;
        cr0 = nr0; cr1 = nr1; cr2 = nr2;
        t = tn;
    }
    process4(cg0, cg1, cg2, cr0, cr1, cr2, acc);

    block_reduce_store(acc, &partial[blockIdx.x]);
}

// Generic fallback (bounds-checked grid-stride), used only if sizes change.
__global__ __launch_bounds__(256, 4) void de_main_gen(const float4* __restrict__ gen,
                                                      const float4* __restrict__ gt,
                                                      float* __restrict__ partial,
                                                      int ntrip) {
    int tid = blockIdx.x * blockDim.x + threadIdx.x;
    int stride = gridDim.x * blockDim.x;
    float acc = 0.0f;
    for (int t = tid; t < ntrip; t += stride) {
        float4 g0 = gen[3 * t + 0], g1 = gen[3 * t + 1], g2 = gen[3 * t + 2];
        float4 r0 = gt [3 * t + 0], r1 = gt [3 * t + 1], r2 = gt [3 * t + 2];
        process4(g0, g1, g2, r0, r1, r2, acc);
    }
    block_reduce_store(acc, &partial[blockIdx.x]);
}

__global__ __launch_bounds__(256) void de_final(const float* __restrict__ partial,
                                                float* __restrict__ out,
                                                int n, float inv_npix) {
    float acc = 0.0f;
    for (int i = threadIdx.x; i < n; i += 256) acc += partial[i];
    for (int off = 32; off > 0; off >>= 1) acc += __shfl_down(acc, off, 64);
    __shared__ float sm[4];
    int lane = threadIdx.x & 63;
    int wid  = threadIdx.x >> 6;
    if (lane == 0) sm[wid] = acc;
    __syncthreads();
    if (threadIdx.x == 0) out[0] = (sm[0] + sm[1] + sm[2] + sm[3]) * inv_npix;
}

extern "C" void kernel_launch(void* const* d_in, const int* in_sizes, int n_in,
                              void* d_out, int out_size, void* d_ws, size_t ws_size,
                              hipStream_t stream) {
    const float4* gen = (const float4*)d_in[0];  // genImage
    const float4* gt  = (const float4*)d_in[1];  // gtImage

    const int total_f = in_sizes[0];             // 25,165,824 floats
    const int ntrip   = total_f / 12;            // 4-pixel work items
    const int npix    = total_f / 3;

    float* partial = (float*)d_ws;
    const int blocks  = 2048;
    const int threads = blocks * 256;

    if (ntrip == threads * 4) {
        de_main_fix<4><<<blocks, 256, 0, stream>>>(gen, gt, partial, threads);
    } else {
        de_main_gen<<<blocks, 256, 0, stream>>>(gen, gt, partial, ntrip);
    }
    de_final<<<1, 256, 0, stream>>>(partial, (float*)d_out,
                                    blocks, 1.0f / (float)npix);
}